// Round 5
// baseline (695.404 us; speedup 1.0000x reference)
//
#include <hip/hip_runtime.h>
#include <hip/hip_bf16.h>
#include <hip/hip_cooperative_groups.h>
#include <math.h>

namespace cg = cooperative_groups;

#define NROW 8
#define DT   2097152   // D = D1*D2
#define DD1  2048
#define DD2  1024
#define BATCH 512
#define NGRP 2048      // groups of (256 threads x 4 cols) covering DT

// ws layout (~102.8 MB):
//  [0)           vsum : NROW*DT floats            (67,108,864 B)   (xb bf16 reuses this after k_wt)
//  [67108864)    code : DT bytes                  ( 2,097,152 B)
//  [69206016)    wt   : NROW*DT bf16 [n][l][k]    (33,554,432 B)
//  [102760448)   meta : u32[1412]  (hist2 [4..132), hist3 [132..260),
//                        final_rank [260..388), msp_tab f32[896] @388, bits [1284..1412))
//  [102768640)   slots: u32[6144]  (smax [0..2048), smin [2048..4096), gmax [4096..6144))

typedef __attribute__((ext_vector_type(8))) short short8;
typedef __attribute__((ext_vector_type(4))) float f32x4;

__device__ __forceinline__ unsigned fenc(float f){
  unsigned u = __float_as_uint(f);
  return (u & 0x80000000u) ? ~u : (u | 0x80000000u);
}
__device__ __forceinline__ float fdec(unsigned k){
  return (k & 0x80000000u) ? __uint_as_float(k ^ 0x80000000u) : __uint_as_float(~k);
}
__device__ __forceinline__ float sigmoid_ref(float z){
  #pragma clang fp contract(off)
  return 1.0f / (1.0f + expf(-z));
}
__device__ __forceinline__ unsigned short f2bf(float f){
  __hip_bfloat16 h = __float2bfloat16(f);
  return *reinterpret_cast<unsigned short*>(&h);
}
// consistent level-1 base across ALL phases: s1*floor(u*inv_s1)
__device__ __forceinline__ float base1(float u, float s1, float inv_s1){
  #pragma clang fp contract(off)
  return s1 * floorf(u * inv_s1);
}
__device__ __forceinline__ void async16(const unsigned short* g, unsigned short* l){
  __builtin_amdgcn_global_load_lds((const __attribute__((address_space(1))) unsigned int*)g,
                                   (__attribute__((address_space(3))) unsigned int*)l, 16, 0, 0);
}

// ---- 8-element sorting networks (Batcher odd-even, 19 comparators) ----
#define CSWAPV(a,b) { float _lo=fminf(a,b), _hi=fmaxf(a,b); a=_lo; b=_hi; }
__device__ __forceinline__ void sort8v(float v[8]){
  CSWAPV(v[0],v[1]) CSWAPV(v[2],v[3]) CSWAPV(v[4],v[5]) CSWAPV(v[6],v[7])
  CSWAPV(v[0],v[2]) CSWAPV(v[1],v[3]) CSWAPV(v[4],v[6]) CSWAPV(v[5],v[7])
  CSWAPV(v[1],v[2]) CSWAPV(v[5],v[6])
  CSWAPV(v[0],v[4]) CSWAPV(v[1],v[5]) CSWAPV(v[2],v[6]) CSWAPV(v[3],v[7])
  CSWAPV(v[2],v[4]) CSWAPV(v[3],v[5])
  CSWAPV(v[1],v[2]) CSWAPV(v[3],v[4]) CSWAPV(v[5],v[6])
}
__device__ __forceinline__ void cswapkv(float&av,int&ai,float&bv,int&bi){
  bool sw = (av > bv) || ((av == bv) && (ai > bi));   // lexicographic -> stable
  float nav = sw ? bv : av; float nbv = sw ? av : bv;
  int   nai = sw ? bi : ai; int   nbi = sw ? ai : bi;
  av = nav; bv = nbv; ai = nai; bi = nbi;
}
#define CSWAPK(i,j) cswapkv(v[i],ix[i],v[j],ix[j]);
__device__ __forceinline__ void sort8kv(float v[8], int ix[8]){
  CSWAPK(0,1) CSWAPK(2,3) CSWAPK(4,5) CSWAPK(6,7)
  CSWAPK(0,2) CSWAPK(1,3) CSWAPK(4,6) CSWAPK(5,7)
  CSWAPK(1,2) CSWAPK(5,6)
  CSWAPK(0,4) CSWAPK(1,5) CSWAPK(2,6) CSWAPK(3,7)
  CSWAPK(2,4) CSWAPK(3,5)
  CSWAPK(1,2) CSWAPK(3,4) CSWAPK(5,6)
}

// ---- phase helpers ----

template<int LEVEL>
__device__ __forceinline__ void passB_group(
    int d0, const float* __restrict__ U, const float* __restrict__ vsum,
    const float* __restrict__ tm, float s1, float inv_s1, float inv_gmax,
    unsigned char* __restrict__ code, int* hist){
  #pragma clang fp contract(off)
  float4 u[8], b[8];
  #pragma unroll
  for (int i = 0; i < 8; ++i){
    u[i] = *(const float4*)(U + (size_t)i*DT + d0);
    if (LEVEL == 2){
      float4 bb;
      bb.x = base1(u[i].x, s1, inv_s1); bb.y = base1(u[i].y, s1, inv_s1);
      bb.z = base1(u[i].z, s1, inv_s1); bb.w = base1(u[i].w, s1, inv_s1);
      b[i] = bb;
    } else {
      b[i] = *(const float4*)(vsum + (size_t)i*DT + d0);
    }
  }
  float thr = sigmoid_ref(tm[d0 >> 11]);
  uchar4 cods;
  unsigned char* cp = (unsigned char*)&cods;
  #pragma unroll
  for (int c = 0; c < 4; ++c){
    float res[8];
    #pragma unroll
    for (int i = 0; i < 8; ++i) res[i] = ((const float*)&u[i])[c] - ((const float*)&b[i])[c];
    sort8v(res);
    int cd = 0;
    #pragma unroll
    for (int i = 0; i < 7; ++i){
      // bit = rint(sigmoid((dn-thr)/0.01)) == (dn > thr)
      float dn = (res[i+1] - res[i]) * inv_gmax;
      cd = (cd << 1) | ((dn > thr) ? 1 : 0);
    }
    cp[c] = (unsigned char)cd;
    atomicAdd(&hist[cd], 1);
  }
  *(uchar4*)(code + d0) = cods;
}

// returns encoded max sorted-residual delta of NEXT level (LEVEL==2 only)
template<int LEVEL>
__device__ __forceinline__ unsigned passD_group(
    int d0, int t, const float* __restrict__ U, float* __restrict__ vsum,
    const unsigned char* __restrict__ code,
    float s1, float inv_s1, float s, float inv_s,
    const int* fr_s, const unsigned* bits_s, const float* msp_s, float* q_lds){
  #pragma clang fp contract(off)
  float4 u4[8], b4[8];
  #pragma unroll
  for (int i = 0; i < 8; ++i){
    u4[i] = *(const float4*)(U + (size_t)i*DT + d0);
    if (LEVEL == 2){
      float4 bb;
      bb.x = base1(u4[i].x, s1, inv_s1); bb.y = base1(u4[i].y, s1, inv_s1);
      bb.z = base1(u4[i].z, s1, inv_s1); bb.w = base1(u4[i].w, s1, inv_s1);
      b4[i] = bb;
    } else {
      b4[i] = *(const float4*)(vsum + (size_t)i*DT + d0);
    }
  }
  uchar4 cods = *(const uchar4*)(code + d0);
  const unsigned char* cp = (const unsigned char*)&cods;
  #pragma unroll
  for (int c = 0; c < 4; ++c){
    float v[8]; int ix[8];
    #pragma unroll
    for (int i = 0; i < 8; ++i){
      v[i] = ((const float*)&u4[i])[c] - ((const float*)&b4[i])[c];
      ix[i] = i;
    }
    sort8kv(v, ix);                        // stable: reproduces jnp.argsort
    int cr = fr_s[cp[c]];
    unsigned sb = bits_s[cr];
    float vv[8]; bool bl[8];
    float buf = 0.0f, cnt = 0.0f, g = 1.0f; bool reset = false;
    #pragma unroll
    for (int i = 0; i < 8; ++i){           // reference scan; mean via rcp (<=1.5ulp)
      buf = reset ? v[i] : (buf + v[i]);
      cnt = reset ? 1.0f : (cnt + 1.0f);
      g   = reset ? 1.0f : g;
      float m = buf * __builtin_amdgcn_rcpf(cnt);
      if (i == 7){ vv[7] = g * m; bl[7] = true; }
      else {
        float msp = msp_s[cr*7 + i];
        bool b = ((sb >> i) & 1u) != 0u;
        vv[i] = b ? ((g * msp) * m) : 0.0f;
        bl[i] = b;
        g = b ? g : (g * (1.0f - msp));
        reset = b;
      }
    }
    float out = vv[7];
    float inner[8];
    inner[7] = out;
    for (int i = 6; i >= 0; --i){ if (bl[i]) out = vv[i]; inner[i] = out; }
    #pragma unroll
    for (int i = 0; i < 8; ++i){           // scatter q to original-row slot; bank = t%32, conflict-free
      float q = s * floorf(inner[i] * inv_s);
      q_lds[(ix[i]*4 + c)*256 + t] = q;
    }
  }
  float4 vn4[8];
  unsigned dmax = 0u;
  #pragma unroll
  for (int c = 0; c < 4; ++c){
    float res3[8];
    #pragma unroll
    for (int rr = 0; rr < 8; ++rr){
      float q = q_lds[(rr*4 + c)*256 + t];
      float vn = ((const float*)&b4[rr])[c] + q;
      ((float*)&vn4[rr])[c] = vn;
      if (LEVEL == 2) res3[rr] = ((const float*)&u4[rr])[c] - vn;  // bit-exact next residual
    }
    if (LEVEL == 2){
      sort8v(res3);
      float m = 0.0f;
      #pragma unroll
      for (int i = 0; i < 7; ++i) m = fmaxf(m, res3[i+1] - res3[i]);
      dmax = max(dmax, __float_as_uint(m));
    }
  }
  #pragma unroll
  for (int rr = 0; rr < 8; ++rr)
    *(float4*)(vsum + (size_t)rr*DT + d0) = vn4[rr];
  return dmax;
}

template<int LEVEL>
__device__ void small_phase(const float* __restrict__ U, const float* __restrict__ vsum,
                            const float* __restrict__ tm, unsigned* __restrict__ meta,
                            float s1, float inv_s1, float gmax, float* q_lds){
  #pragma clang fp contract(off)
  int c = threadIdx.x;                     // 256 threads participate; work guarded to c<128
  int* cs   = (int*)q_lds;
  int* rk   = cs + 128;
  int* redk = rk + 128;
  int* tc   = redk + 128;
  int* tr   = tc + 8;
  int* w0c  = tr + 8;
  if (c < 128) cs[c] = (int)meta[((LEVEL==2)?4:132) + c];
  __syncthreads();
  if (c < 128){
    bool present = cs[c] > 0;
    unsigned long long bm = __ballot(present);
    int lane = c & 63;
    rk[c] = (int)__popcll(bm & ((1ull << lane) - 1ull));
    if (c == 63) *w0c = (int)__popcll(bm);
  }
  __syncthreads();
  if (c >= 64 && c < 128) rk[c] += *w0c;
  __syncthreads();
  for (int k = 0; k < 5; ++k){             // top-5 argsort(-counts), ties -> lowest index
    if (c < 128) redk[c] = (cs[c] << 7) | (127 - c);
    __syncthreads();
    for (int o = 64; o > 0; o >>= 1){
      if (c < o) redk[c] = max(redk[c], redk[c+o]);
      __syncthreads();
    }
    if (c == 0){
      int best = 127 - (redk[0] & 127);
      tc[k] = best; tr[k] = rk[best];
      cs[best] = -1;
    }
    __syncthreads();
  }
  if (c < 128){
    int besti = -1, sel = 0;
    #pragma unroll
    for (int j = 0; j < 5; ++j){
      int inter = __popc(c & tc[j]);
      if (inter > besti){ besti = inter; sel = j; }
    }
    bool is_top = false;
    #pragma unroll
    for (int j = 0; j < 5; ++j) is_top = is_top || (rk[c] == tr[j]);
    ((int*)meta)[260 + c] = is_top ? rk[c] : tr[sel];
    // full-fidelity msp/scheme for columns 0..127 (values multiply into w)
    float res[8];
    #pragma unroll
    for (int i = 0; i < 8; ++i){
      size_t off = (size_t)i*DT + c;
      float u = U[off];
      float b = (LEVEL==2) ? base1(u, s1, inv_s1) : vsum[off];
      res[i] = u - b;
    }
    sort8v(res);
    float thr = sigmoid_ref(tm[c >> 11]);
    unsigned bits = 0;
    float* msp_tab = (float*)(meta + 388);
    #pragma unroll
    for (int i = 0; i < 7; ++i){
      float dn  = (res[i+1] - res[i]) / gmax;
      float z   = (dn - thr) / 0.01f;
      float msp = sigmoid_ref(z);
      msp_tab[c*7 + i] = msp;
      bits |= ((unsigned)(int)rintf(msp)) << i;
    }
    meta[1284 + c] = bits;
  }
  __syncthreads();
}

// ---- the fused cooperative quant kernel ----
__global__ void __launch_bounds__(256, 4) k_quant(
    const float* __restrict__ U, const float* __restrict__ tm,
    float* __restrict__ vsum, unsigned char* __restrict__ code,
    unsigned* __restrict__ meta, unsigned* __restrict__ slots){
  #pragma clang fp contract(off)
  cg::grid_group grid = cg::this_grid();
  int t = threadIdx.x, b = blockIdx.x, nb = gridDim.x;

  __shared__ __align__(16) float q_lds[32*256];   // 32 KB; overlaid as hist / small-phase scratch
  __shared__ int fr_s[128];
  __shared__ unsigned bits_s[128];
  __shared__ float msp_s[896];
  __shared__ unsigned redA[256], redB[256];

  // ---- P1: global min/max (+ zero histograms)
  if (b == 0 && t < 128){ meta[4+t] = 0u; meta[132+t] = 0u; }
  float mx = -INFINITY, mn = INFINITY;
  for (int grp = b; grp < NGRP; grp += nb){
    int d0 = grp*1024 + t*4;
    #pragma unroll
    for (int i = 0; i < 8; ++i){
      float4 v = *(const float4*)(U + (size_t)i*DT + d0);
      mx = fmaxf(mx, fmaxf(fmaxf(v.x,v.y), fmaxf(v.z,v.w)));
      mn = fminf(mn, fminf(fminf(v.x,v.y), fminf(v.z,v.w)));
    }
  }
  redA[t] = fenc(mx); redB[t] = fenc(mn);
  __syncthreads();
  for (int o = 128; o > 0; o >>= 1){
    if (t < o){ redA[t] = max(redA[t], redA[t+o]); redB[t] = min(redB[t], redB[t+o]); }
    __syncthreads();
  }
  if (t == 0){ slots[b] = redA[0]; slots[2048 + b] = redB[0]; }
  grid.sync();                                              // S1
  // all-blocks redundant reduce (order-independent max/min -> identical everywhere)
  {
    unsigned vx = 0u, vn = 0xFFFFFFFFu;
    for (int i = t; i < nb; i += 256){ vx = max(vx, slots[i]); vn = min(vn, slots[2048+i]); }
    __syncthreads();
    redA[t] = vx; redB[t] = vn;
    __syncthreads();
    for (int o = 128; o > 0; o >>= 1){
      if (t < o){ redA[t] = max(redA[t], redA[t+o]); redB[t] = min(redB[t], redB[t+o]); }
      __syncthreads();
    }
  }
  float beta = fdec(redA[0]), alpha = fdec(redB[0]);
  __syncthreads();
  float s1 = (beta - alpha) / 3.0f;
  float inv_s1 = 1.0f / s1;
  float s2 = s1 / 5.0f, s3 = s2 / 17.0f;
  float inv_s2 = 1.0f / s2, inv_s3 = 1.0f / s3;

  // ---- P2: level-2 gmax (max sorted-residual delta)
  unsigned dmax = 0u;
  for (int grp = b; grp < NGRP; grp += nb){
    int d0 = grp*1024 + t*4;
    float4 u[8];
    #pragma unroll
    for (int i = 0; i < 8; ++i) u[i] = *(const float4*)(U + (size_t)i*DT + d0);
    #pragma unroll
    for (int c = 0; c < 4; ++c){
      float res[8];
      #pragma unroll
      for (int i = 0; i < 8; ++i){
        float uv = ((const float*)&u[i])[c];
        res[i] = uv - base1(uv, s1, inv_s1);
      }
      sort8v(res);
      float m = 0.0f;
      #pragma unroll
      for (int i = 0; i < 7; ++i) m = fmaxf(m, res[i+1] - res[i]);
      dmax = max(dmax, __float_as_uint(m));   // deltas >= 0: bits order-preserving
    }
  }
  redA[t] = dmax;
  __syncthreads();
  for (int o = 128; o > 0; o >>= 1){
    if (t < o) redA[t] = max(redA[t], redA[t+o]);
    __syncthreads();
  }
  if (t == 0) slots[4096 + b] = redA[0];
  grid.sync();                                              // S2
  {
    unsigned vx = 0u;
    for (int i = t; i < nb; i += 256) vx = max(vx, slots[4096+i]);
    __syncthreads();
    redA[t] = vx;
    __syncthreads();
    for (int o = 128; o > 0; o >>= 1){
      if (t < o) redA[t] = max(redA[t], redA[t+o]);
      __syncthreads();
    }
  }
  float gmax2 = __uint_as_float(redA[0]);
  __syncthreads();
  float inv_gmax2 = 1.0f / gmax2;

  // ---- P3: level-2 codes + histogram
  int* hist = (int*)q_lds;
  if (t < 128) hist[t] = 0;
  __syncthreads();
  for (int grp = b; grp < NGRP; grp += nb)
    passB_group<2>(grp*1024 + t*4, U, vsum, tm, s1, inv_s1, inv_gmax2, code, hist);
  __syncthreads();
  if (t < 128){ int h = hist[t]; if (h) atomicAdd((int*)&meta[4+t], h); }
  grid.sync();                                              // S3
  // ---- P4: level-2 rank/top-5/msp tables (block 0)
  if (b == 0) small_phase<2>(U, vsum, tm, meta, s1, inv_s1, gmax2, q_lds);
  grid.sync();                                              // S4
  // ---- P5: level-2 quant apply (+ fused level-3 gmax)
  if (t < 128){ fr_s[t] = ((const int*)meta)[260+t]; bits_s[t] = meta[1284+t]; }
  for (int i = t; i < 896; i += 256) msp_s[i] = ((const float*)(meta+388))[i];
  __syncthreads();
  unsigned dmax3 = 0u;
  for (int grp = b; grp < NGRP; grp += nb)
    dmax3 = max(dmax3, passD_group<2>(grp*1024 + t*4, t, U, vsum, code,
                                      s1, inv_s1, s2, inv_s2, fr_s, bits_s, msp_s, q_lds));
  __syncthreads();
  redA[t] = dmax3;
  __syncthreads();
  for (int o = 128; o > 0; o >>= 1){
    if (t < o) redA[t] = max(redA[t], redA[t+o]);
    __syncthreads();
  }
  if (t == 0) slots[4096 + b] = redA[0];
  grid.sync();                                              // S5
  {
    unsigned vx = 0u;
    for (int i = t; i < nb; i += 256) vx = max(vx, slots[4096+i]);
    __syncthreads();
    redA[t] = vx;
    __syncthreads();
    for (int o = 128; o > 0; o >>= 1){
      if (t < o) redA[t] = max(redA[t], redA[t+o]);
      __syncthreads();
    }
  }
  float gmax3 = __uint_as_float(redA[0]);
  __syncthreads();
  float inv_gmax3 = 1.0f / gmax3;

  // ---- P6: level-3 codes + histogram (base = vsum)
  if (t < 128) hist[t] = 0;
  __syncthreads();
  for (int grp = b; grp < NGRP; grp += nb)
    passB_group<3>(grp*1024 + t*4, U, vsum, tm, s1, inv_s1, inv_gmax3, code, hist);
  __syncthreads();
  if (t < 128){ int h = hist[t]; if (h) atomicAdd((int*)&meta[132+t], h); }
  grid.sync();                                              // S6
  // ---- P7: level-3 tables (block 0)
  if (b == 0) small_phase<3>(U, vsum, tm, meta, s1, inv_s1, gmax3, q_lds);
  grid.sync();                                              // S7
  // ---- P8: level-3 quant apply -> final vsum
  if (t < 128){ fr_s[t] = ((const int*)meta)[260+t]; bits_s[t] = meta[1284+t]; }
  for (int i = t; i < 896; i += 256) msp_s[i] = ((const float*)(meta+388))[i];
  __syncthreads();
  for (int grp = b; grp < NGRP; grp += nb)
    passD_group<3>(grp*1024 + t*4, t, U, vsum, code,
                   s1, inv_s1, s3, inv_s3, fr_s, bits_s, msp_s, q_lds);
}

// transpose + convert: wt[n][l][k] = bf16(vsum[n][k][l]); 64(k) x 64(l) tiles
__global__ __launch_bounds__(256) void k_wt(const float* __restrict__ vsum, unsigned short* __restrict__ wt){
  __shared__ unsigned short tile[64][68];
  int t = threadIdx.x;
  int c4 = t & 15, r0 = t >> 4;
  int n = blockIdx.z, k0 = blockIdx.y*64, l0 = blockIdx.x*64;
  const float* src = vsum + (size_t)n*DT;
  #pragma unroll
  for (int i = 0; i < 4; ++i){
    int r = r0 + i*16;
    float4 v = *(const float4*)(src + (size_t)(k0+r)*DD2 + l0 + c4*4);
    tile[r][c4*4+0] = f2bf(v.x); tile[r][c4*4+1] = f2bf(v.y);
    tile[r][c4*4+2] = f2bf(v.z); tile[r][c4*4+3] = f2bf(v.w);
  }
  __syncthreads();
  unsigned short* dst = wt + (size_t)n*DT;
  #pragma unroll
  for (int i = 0; i < 4; ++i){
    int rl = r0 + i*16;
    ushort4 o;
    o.x = tile[c4*4+0][rl]; o.y = tile[c4*4+1][rl];
    o.z = tile[c4*4+2][rl]; o.w = tile[c4*4+3][rl];
    *(ushort4*)(dst + (size_t)(l0+rl)*DD1 + k0 + c4*4) = o;
  }
}

// x fp32 -> bf16, same layout
__global__ __launch_bounds__(256) void k_xb(const float* __restrict__ x, unsigned short* __restrict__ xb){
  int idx = (blockIdx.x*256 + threadIdx.x)*4;
  float4 v = *(const float4*)(x + idx);
  ushort4 o;
  o.x = f2bf(v.x); o.y = f2bf(v.y); o.z = f2bf(v.z); o.w = f2bf(v.w);
  *(ushort4*)(xb + idx) = o;
}

// MFMA GEMM: out[b,n,l] = sum_k xb[b,n,k] * wt[n,l,k]; 64(M)x128(N) tile, BK=64, 4 waves
__global__ __launch_bounds__(256) void k_gemm(const unsigned short* __restrict__ xb,
                                              const unsigned short* __restrict__ wt,
                                              float* __restrict__ out){
  __shared__ __align__(16) unsigned short As[64*64];
  __shared__ __align__(16) unsigned short Bs[128*64];
  int t = threadIdx.x;
  int lane = t & 63, wv = t >> 6;
  int n  = blockIdx.z;
  int b0 = blockIdx.y * 64;
  int l0 = blockIdx.x * 128;
  int wm = (wv >> 1) * 32, wn = (wv & 1) * 64;
  int col = lane & 15, quad = lane >> 4;
  int arow = lane >> 3, aseg = lane & 7;
  const unsigned short* wtn = wt + (size_t)n*DT;
  f32x4 acc[2][4] = {};
  for (int k0 = 0; k0 < DD1; k0 += 64){
    #pragma unroll
    for (int i = 0; i < 2; ++i){
      int row = wv*16 + i*8 + arow;
      const unsigned short* g = xb + (((size_t)(b0+row)*NROW + n)*DD1 + k0 + aseg*8);
      async16(g, &As[(wv*16 + i*8)*64]);
    }
    #pragma unroll
    for (int i = 0; i < 4; ++i){
      int row = wv*32 + i*8 + arow;
      const unsigned short* g = wtn + ((size_t)(l0+row)*DD1 + k0 + aseg*8);
      async16(g, &Bs[(wv*32 + i*8)*64]);
    }
    __syncthreads();
    #pragma unroll
    for (int ks = 0; ks < 2; ++ks){
      int kq = ks*32 + quad*8;
      short8 af[2], bfr[4];
      #pragma unroll
      for (int mi = 0; mi < 2; ++mi) af[mi]  = *(const short8*)&As[(wm + mi*16 + col)*64 + kq];
      #pragma unroll
      for (int ni = 0; ni < 4; ++ni) bfr[ni] = *(const short8*)&Bs[(wn + ni*16 + col)*64 + kq];
      #pragma unroll
      for (int mi = 0; mi < 2; ++mi)
        #pragma unroll
        for (int ni = 0; ni < 4; ++ni)
          acc[mi][ni] = __builtin_amdgcn_mfma_f32_16x16x32_bf16(af[mi], bfr[ni], acc[mi][ni], 0, 0, 0);
    }
    __syncthreads();
  }
  #pragma unroll
  for (int mi = 0; mi < 2; ++mi)
    #pragma unroll
    for (int ni = 0; ni < 4; ++ni)
      #pragma unroll
      for (int r = 0; r < 4; ++r){
        int bb = b0 + wm + mi*16 + quad*4 + r;
        int l = l0 + wn + ni*16 + col;
        out[((size_t)bb*NROW + n)*DD2 + l] = acc[mi][ni][r];
      }
}

extern "C" void kernel_launch(void* const* d_in, const int* in_sizes, int n_in,
                              void* d_out, int out_size, void* d_ws, size_t ws_size,
                              hipStream_t stream){
  const float* x  = (const float*)d_in[0];
  const float* U  = (const float*)d_in[1];
  const float* tm = (const float*)d_in[2];
  float* out  = (float*)d_out;
  float* vsum = (float*)d_ws;
  unsigned char* code = (unsigned char*)d_ws + 67108864;
  unsigned short* wt  = (unsigned short*)((unsigned char*)d_ws + 69206016);
  unsigned* meta  = (unsigned*)((unsigned char*)d_ws + 102760448);
  unsigned* slots = (unsigned*)((unsigned char*)d_ws + 102768640);
  unsigned short* xb = (unsigned short*)d_ws;   // overlaps vsum; written only after k_wt
  (void)in_sizes; (void)n_in; (void)out_size; (void)ws_size;

  // cooperative grid: guaranteed 4 blocks/CU by __launch_bounds__(256,4) + 39.4 KB LDS
  int mb = 0;
  hipOccupancyMaxActiveBlocksPerMultiprocessor(&mb, k_quant, 256, 0);
  int grid = mb * 256;
  if (grid > 1024) grid = 1024;
  if (grid < 1)    grid = 256;
  const float* U_ = U; const float* tm_ = tm;
  float* vs_ = vsum; unsigned char* cd_ = code; unsigned* mt_ = meta; unsigned* sl_ = slots;
  void* args[] = { (void*)&U_, (void*)&tm_, (void*)&vs_, (void*)&cd_, (void*)&mt_, (void*)&sl_ };
  hipLaunchCooperativeKernel((void*)k_quant, dim3(grid), dim3(256), args, 0, stream);

  // epilogue
  k_wt  <<<dim3(DD2/64, DD1/64, NROW), 256, 0, stream>>>(vsum, wt);
  k_xb  <<<(BATCH*NROW*DD1)/1024, 256, 0, stream>>>(x, xb);
  k_gemm<<<dim3(DD2/128, BATCH/64, NROW), 256, 0, stream>>>(xb, wt, out);
}

// Round 6
// 399.224 us; speedup vs baseline: 1.7419x; 1.7419x over previous
//
#include <hip/hip_runtime.h>
#include <hip/hip_bf16.h>
#include <math.h>

#define NROW 8
#define DT   2097152   // D = D1*D2
#define DD1  2048
#define DD2  1024
#define BATCH 512
#define NBLK 2048      // pass kernels: 2048 blocks x 256 thr x 4 cols == DT

// ws layout (~98.0 MiB):
//  [0)          mcode : NROW*DT uint8  (16,777,216 B)  level-2 m (+8 bias)
//  [16777216)   vsumb : NROW*DT bf16   (33,554,432 B)  final vsum, [n][k][l]
//  [50331648)   xb    : bf16 x         (16,777,216 B)
//  [67108864)   code  : DT bytes       ( 2,097,152 B)
//  [69206016)   wt    : NROW*DT bf16   (33,554,432 B)  [n][l][k]
//  [102760448)  meta  : u32[1412] (hist2 @4, hist3 @132, final_rank @260,
//                        msp f32[896] @388, bits @1284)
//  [102768640)  slots : u32[8192] (SMAX 0, SMIN 2048, G2 4096, G3 6144)

#define SL_SMAX 0
#define SL_SMIN 2048
#define SL_G2   4096
#define SL_G3   6144

typedef __attribute__((ext_vector_type(8))) short short8;
typedef __attribute__((ext_vector_type(4))) float f32x4;

__device__ __forceinline__ unsigned fenc(float f){
  unsigned u = __float_as_uint(f);
  return (u & 0x80000000u) ? ~u : (u | 0x80000000u);
}
__device__ __forceinline__ float fdec(unsigned k){
  return (k & 0x80000000u) ? __uint_as_float(k ^ 0x80000000u) : __uint_as_float(~k);
}
__device__ __forceinline__ float sigmoid_ref(float z){
  #pragma clang fp contract(off)
  return 1.0f / (1.0f + expf(-z));
}
__device__ __forceinline__ unsigned short f2bf(float f){
  __hip_bfloat16 h = __float2bfloat16(f);
  return *reinterpret_cast<unsigned short*>(&h);
}
// consistent level-1 base across ALL kernels
__device__ __forceinline__ float base1(float u, float s1, float inv_s1){
  #pragma clang fp contract(off)
  return s1 * floorf(u * inv_s1);
}
__device__ __forceinline__ void async16(const unsigned short* g, unsigned short* l){
  __builtin_amdgcn_global_load_lds((const __attribute__((address_space(1))) unsigned int*)g,
                                   (__attribute__((address_space(3))) unsigned int*)l, 16, 0, 0);
}

// ---- 8-element sorting networks (Batcher odd-even, 19 comparators) ----
#define CSWAPV(a,b) { float _lo=fminf(a,b), _hi=fmaxf(a,b); a=_lo; b=_hi; }
__device__ __forceinline__ void sort8v(float v[8]){
  CSWAPV(v[0],v[1]) CSWAPV(v[2],v[3]) CSWAPV(v[4],v[5]) CSWAPV(v[6],v[7])
  CSWAPV(v[0],v[2]) CSWAPV(v[1],v[3]) CSWAPV(v[4],v[6]) CSWAPV(v[5],v[7])
  CSWAPV(v[1],v[2]) CSWAPV(v[5],v[6])
  CSWAPV(v[0],v[4]) CSWAPV(v[1],v[5]) CSWAPV(v[2],v[6]) CSWAPV(v[3],v[7])
  CSWAPV(v[2],v[4]) CSWAPV(v[3],v[5])
  CSWAPV(v[1],v[2]) CSWAPV(v[3],v[4]) CSWAPV(v[5],v[6])
}
__device__ __forceinline__ void cswapkv(float&av,int&ai,float&bv,int&bi){
  bool sw = (av > bv) || ((av == bv) && (ai > bi));   // lexicographic -> stable
  float nav = sw ? bv : av; float nbv = sw ? av : bv;
  int   nai = sw ? bi : ai; int   nbi = sw ? ai : bi;
  av = nav; bv = nbv; ai = nai; bi = nbi;
}
#define CSWAPK(i,j) cswapkv(v[i],ix[i],v[j],ix[j]);
__device__ __forceinline__ void sort8kv(float v[8], int ix[8]){
  CSWAPK(0,1) CSWAPK(2,3) CSWAPK(4,5) CSWAPK(6,7)
  CSWAPK(0,2) CSWAPK(1,3) CSWAPK(4,6) CSWAPK(5,7)
  CSWAPK(1,2) CSWAPK(5,6)
  CSWAPK(0,4) CSWAPK(1,5) CSWAPK(2,6) CSWAPK(3,7)
  CSWAPK(2,4) CSWAPK(3,5)
  CSWAPK(1,2) CSWAPK(3,4) CSWAPK(5,6)
}

// slot reduces (redundant, per consumer block; order-independent -> identical results)
template<int BD>
__device__ __forceinline__ unsigned slots_max(const unsigned* s, unsigned* red, int t){
  unsigned v = 0u;
  for (int i = t; i < NBLK; i += BD) v = max(v, s[i]);
  red[t] = v; __syncthreads();
  for (int o = BD/2; o > 0; o >>= 1){ if (t < o) red[t] = max(red[t], red[t+o]); __syncthreads(); }
  unsigned r = red[0]; __syncthreads(); return r;
}
template<int BD>
__device__ __forceinline__ unsigned slots_min(const unsigned* s, unsigned* red, int t){
  unsigned v = 0xFFFFFFFFu;
  for (int i = t; i < NBLK; i += BD) v = min(v, s[i]);
  red[t] = v; __syncthreads();
  for (int o = BD/2; o > 0; o >>= 1){ if (t < o) red[t] = min(red[t], red[t+o]); __syncthreads(); }
  unsigned r = red[0]; __syncthreads(); return r;
}
template<int BD>
__device__ __forceinline__ float get_s1(const unsigned* slots, unsigned* red, int t){
  float beta  = fdec(slots_max<BD>(slots + SL_SMAX, red, t));
  float alpha = fdec(slots_min<BD>(slots + SL_SMIN, red, t));
  return (beta - alpha) / 3.0f;
}
// reconstruct level-2 vsum from u + stored m byte (bit-exact vs producer)
__device__ __forceinline__ float vn2_of(float u, unsigned char mb, float s1, float inv_s1, float s2){
  #pragma clang fp contract(off)
  return base1(u, s1, inv_s1) + s2 * (float)((int)mb - 8);
}

// ---- P1: global min/max of U + x->bf16 convert + zero hists (no atomics) ----
__global__ __launch_bounds__(256) void k_mmxb(const float* __restrict__ U, const float* __restrict__ x,
                                              unsigned short* __restrict__ xb,
                                              unsigned* __restrict__ meta, unsigned* __restrict__ slots){
  __shared__ unsigned redA[256], redB[256];
  int t = threadIdx.x, b = blockIdx.x;
  int gid = b*256 + t;
  if (b == 0 && t < 128){ meta[4+t] = 0u; meta[132+t] = 0u; }
  // x convert: 2,097,152 float4 over 524,288 threads = 4 each
  const float4* x4 = (const float4*)x;
  #pragma unroll
  for (int i = 0; i < 4; ++i){
    int idx = gid + i*524288;
    float4 v = x4[idx];
    ushort4 o;
    o.x = f2bf(v.x); o.y = f2bf(v.y); o.z = f2bf(v.z); o.w = f2bf(v.w);
    *(ushort4*)(xb + (size_t)idx*4) = o;
  }
  // U min/max: 4,194,304 float4 = 8 each
  const float4* U4 = (const float4*)U;
  float mx = -INFINITY, mn = INFINITY;
  #pragma unroll
  for (int i = 0; i < 8; ++i){
    float4 v = U4[gid + i*524288];
    mx = fmaxf(mx, fmaxf(fmaxf(v.x,v.y), fmaxf(v.z,v.w)));
    mn = fminf(mn, fminf(fminf(v.x,v.y), fminf(v.z,v.w)));
  }
  redA[t] = fenc(mx); redB[t] = fenc(mn);
  __syncthreads();
  for (int o = 128; o > 0; o >>= 1){
    if (t < o){ redA[t] = max(redA[t], redA[t+o]); redB[t] = min(redB[t], redB[t+o]); }
    __syncthreads();
  }
  if (t == 0){ slots[SL_SMAX + b] = redA[0]; slots[SL_SMIN + b] = redB[0]; }
}

// ---- P2: level-2 gmax ----
__global__ __launch_bounds__(256) void k_passA2(const float* __restrict__ U,
                                                unsigned* __restrict__ slots){
  #pragma clang fp contract(off)
  __shared__ unsigned red[256];
  int t = threadIdx.x, b = blockIdx.x;
  float s1 = get_s1<256>(slots, red, t);
  float inv_s1 = 1.0f / s1;
  int d0 = (b*256 + t)*4;
  float4 u[8];
  #pragma unroll
  for (int i = 0; i < 8; ++i) u[i] = *(const float4*)(U + (size_t)i*DT + d0);
  unsigned dmax = 0u;
  #pragma unroll
  for (int c = 0; c < 4; ++c){
    float res[8];
    #pragma unroll
    for (int i = 0; i < 8; ++i){
      float uv = ((const float*)&u[i])[c];
      res[i] = uv - base1(uv, s1, inv_s1);
    }
    sort8v(res);
    float m = 0.0f;
    #pragma unroll
    for (int i = 0; i < 7; ++i) m = fmaxf(m, res[i+1] - res[i]);
    dmax = max(dmax, __float_as_uint(m));   // deltas >= 0: bits order-preserving
  }
  red[t] = dmax;
  __syncthreads();
  for (int o = 128; o > 0; o >>= 1){
    if (t < o) red[t] = max(red[t], red[t+o]);
    __syncthreads();
  }
  if (t == 0) slots[SL_G2 + b] = red[0];
}

// ---- P3/P6: codes + histogram ----
template<int LEVEL>
__global__ __launch_bounds__(256) void k_passB(const float* __restrict__ U,
                                               const unsigned char* __restrict__ mcode,
                                               const float* __restrict__ tm,
                                               unsigned char* __restrict__ code,
                                               unsigned* __restrict__ meta, unsigned* __restrict__ slots){
  #pragma clang fp contract(off)
  __shared__ unsigned red[256];
  __shared__ int hist[128];
  int t = threadIdx.x, b = blockIdx.x;
  if (t < 128) hist[t] = 0;
  float s1 = get_s1<256>(slots, red, t);
  float inv_s1 = 1.0f / s1;
  float s2 = s1 / 5.0f;
  float gmax = __uint_as_float(slots_max<256>(slots + ((LEVEL==2)?SL_G2:SL_G3), red, t));
  float inv_gmax = 1.0f / gmax;
  int d0 = (b*256 + t)*4;
  float4 u[8], bb[8];
  #pragma unroll
  for (int i = 0; i < 8; ++i){
    u[i] = *(const float4*)(U + (size_t)i*DT + d0);
    if (LEVEL == 2){
      bb[i].x = base1(u[i].x, s1, inv_s1); bb[i].y = base1(u[i].y, s1, inv_s1);
      bb[i].z = base1(u[i].z, s1, inv_s1); bb[i].w = base1(u[i].w, s1, inv_s1);
    } else {
      uchar4 m4 = *(const uchar4*)(mcode + (size_t)i*DT + d0);
      bb[i].x = vn2_of(u[i].x, m4.x, s1, inv_s1, s2);
      bb[i].y = vn2_of(u[i].y, m4.y, s1, inv_s1, s2);
      bb[i].z = vn2_of(u[i].z, m4.z, s1, inv_s1, s2);
      bb[i].w = vn2_of(u[i].w, m4.w, s1, inv_s1, s2);
    }
  }
  float thr = sigmoid_ref(tm[d0 >> 11]);
  uchar4 cods;
  unsigned char* cp = (unsigned char*)&cods;
  #pragma unroll
  for (int c = 0; c < 4; ++c){
    float res[8];
    #pragma unroll
    for (int i = 0; i < 8; ++i) res[i] = ((const float*)&u[i])[c] - ((const float*)&bb[i])[c];
    sort8v(res);
    int cd = 0;
    #pragma unroll
    for (int i = 0; i < 7; ++i){
      // bit = rint(sigmoid((dn-thr)/0.01)) == (dn > thr)
      float dn = (res[i+1] - res[i]) * inv_gmax;
      cd = (cd << 1) | ((dn > thr) ? 1 : 0);
    }
    cp[c] = (unsigned char)cd;
    atomicAdd(&hist[cd], 1);
  }
  *(uchar4*)(code + d0) = cods;
  __syncthreads();
  if (t < 128){ int h = hist[t]; if (h) atomicAdd((int*)&meta[((LEVEL==2)?4:132) + t], h); }
}

// ---- P4/P7: rank/top-5/msp tables (1 block, 128 threads) ----
template<int LEVEL>
__global__ void k_small(const float* __restrict__ U, const unsigned char* __restrict__ mcode,
                        const float* __restrict__ tm, unsigned* __restrict__ meta,
                        unsigned* __restrict__ slots){
  #pragma clang fp contract(off)
  __shared__ unsigned red[128];
  __shared__ int cs[128], rk[128], redk[128];
  __shared__ int top_code[5], top_rank[5];
  __shared__ int w0cnt;
  int c = threadIdx.x;                    // 128 threads
  float s1 = get_s1<128>(slots, red, c);
  float inv_s1 = 1.0f / s1;
  float s2 = s1 / 5.0f;
  float gmax = __uint_as_float(slots_max<128>(slots + ((LEVEL==2)?SL_G2:SL_G3), red, c));
  cs[c] = (int)meta[((LEVEL==2)?4:132) + c];
  bool present = cs[c] > 0;
  unsigned long long bm = __ballot(present);
  int lane = c & 63;
  int r = (int)__popcll(bm & ((1ull << lane) - 1ull));
  if (c == 63) w0cnt = (int)__popcll(bm);
  __syncthreads();
  if (c >= 64) r += w0cnt;
  rk[c] = r;
  __syncthreads();
  for (int k = 0; k < 5; ++k){            // top-5 argsort(-counts), ties -> lowest index
    redk[c] = (cs[c] << 7) | (127 - c);
    __syncthreads();
    for (int o = 64; o > 0; o >>= 1){
      if (c < o) redk[c] = max(redk[c], redk[c+o]);
      __syncthreads();
    }
    if (c == 0){
      int best = 127 - (redk[0] & 127);
      top_code[k] = best; top_rank[k] = rk[best];
      cs[best] = -1;
    }
    __syncthreads();
  }
  int besti = -1, sel = 0;
  #pragma unroll
  for (int j = 0; j < 5; ++j){            // argmax first-wins over shared-bit counts
    int inter = __popc(c & top_code[j]);
    if (inter > besti){ besti = inter; sel = j; }
  }
  bool is_top = false;
  #pragma unroll
  for (int j = 0; j < 5; ++j) is_top = is_top || (rk[c] == top_rank[j]);
  ((int*)meta)[260 + c] = is_top ? rk[c] : top_rank[sel];
  // full-fidelity msp/scheme for columns 0..127 (values multiply into w)
  float res[8];
  #pragma unroll
  for (int i = 0; i < 8; ++i){
    size_t off = (size_t)i*DT + c;
    float u = U[off];
    float bval = (LEVEL==2) ? base1(u, s1, inv_s1) : vn2_of(u, mcode[off], s1, inv_s1, s2);
    res[i] = u - bval;
  }
  sort8v(res);
  float thr = sigmoid_ref(tm[c >> 11]);
  unsigned bits = 0;
  float* msp_tab = (float*)(meta + 388);
  #pragma unroll
  for (int i = 0; i < 7; ++i){
    float dn  = (res[i+1] - res[i]) / gmax;
    float z   = (dn - thr) / 0.01f;
    float msp = sigmoid_ref(z);
    msp_tab[c*7 + i] = msp;
    bits |= ((unsigned)(int)rintf(msp)) << i;
  }
  meta[1284 + c] = bits;
}

// ---- P5/P8: quant apply. LEVEL==2: write mcode + fused level-3 gmax.
//      LEVEL==3: write final vsum as bf16 [n][k][l]. ----
template<int LEVEL>
__global__ __launch_bounds__(256) void k_passD(const float* __restrict__ U,
                                               unsigned char* __restrict__ mcode,
                                               unsigned short* __restrict__ vsumb,
                                               const unsigned char* __restrict__ code,
                                               unsigned* __restrict__ meta, unsigned* __restrict__ slots){
  #pragma clang fp contract(off)
  __shared__ float q_lds[32*256];          // [rr*4+c][t]: scatter slot, bank = t%32 (conflict-free)
  __shared__ unsigned red[256];
  __shared__ int fr_s[128];
  __shared__ unsigned bits_s[128];
  __shared__ float msp_s[896];
  int t = threadIdx.x, b = blockIdx.x;
  float s1 = get_s1<256>(slots, red, t);
  float inv_s1 = 1.0f / s1;
  float s2 = s1 / 5.0f;
  float s  = (LEVEL == 2) ? s2 : (s2 / 17.0f);
  float inv_s = 1.0f / s;
  if (t < 128){ fr_s[t] = ((const int*)meta)[260+t]; bits_s[t] = meta[1284+t]; }
  for (int i = t; i < 896; i += 256) msp_s[i] = ((const float*)(meta+388))[i];
  __syncthreads();
  int d0 = (b*256 + t)*4;
  float4 u4[8], b4[8];
  #pragma unroll
  for (int i = 0; i < 8; ++i){
    u4[i] = *(const float4*)(U + (size_t)i*DT + d0);
    if (LEVEL == 2){
      b4[i].x = base1(u4[i].x, s1, inv_s1); b4[i].y = base1(u4[i].y, s1, inv_s1);
      b4[i].z = base1(u4[i].z, s1, inv_s1); b4[i].w = base1(u4[i].w, s1, inv_s1);
    } else {
      uchar4 m4 = *(const uchar4*)(mcode + (size_t)i*DT + d0);
      b4[i].x = vn2_of(u4[i].x, m4.x, s1, inv_s1, s2);
      b4[i].y = vn2_of(u4[i].y, m4.y, s1, inv_s1, s2);
      b4[i].z = vn2_of(u4[i].z, m4.z, s1, inv_s1, s2);
      b4[i].w = vn2_of(u4[i].w, m4.w, s1, inv_s1, s2);
    }
  }
  uchar4 cods = *(const uchar4*)(code + d0);
  const unsigned char* cp = (const unsigned char*)&cods;
  #pragma unroll
  for (int c = 0; c < 4; ++c){
    float v[8]; int ix[8];
    #pragma unroll
    for (int i = 0; i < 8; ++i){
      v[i] = ((const float*)&u4[i])[c] - ((const float*)&b4[i])[c];
      ix[i] = i;
    }
    sort8kv(v, ix);                        // stable: reproduces jnp.argsort
    int cr = fr_s[cp[c]];
    unsigned sb = bits_s[cr];
    float vv[8]; bool bl[8];
    float buf = 0.0f, cnt = 0.0f, g = 1.0f; bool reset = false;
    #pragma unroll
    for (int i = 0; i < 8; ++i){           // reference scan; mean via rcp (<=1.5ulp)
      buf = reset ? v[i] : (buf + v[i]);
      cnt = reset ? 1.0f : (cnt + 1.0f);
      g   = reset ? 1.0f : g;
      float m = buf * __builtin_amdgcn_rcpf(cnt);
      if (i == 7){ vv[7] = g * m; bl[7] = true; }
      else {
        float msp = msp_s[cr*7 + i];
        bool bv = ((sb >> i) & 1u) != 0u;
        vv[i] = bv ? ((g * msp) * m) : 0.0f;
        bl[i] = bv;
        g = bv ? g : (g * (1.0f - msp));
        reset = bv;
      }
    }
    float out = vv[7];
    float inner[8];
    inner[7] = out;
    for (int i = 6; i >= 0; --i){ if (bl[i]) out = vv[i]; inner[i] = out; }
    #pragma unroll
    for (int i = 0; i < 8; ++i){           // scatter floor-count to original-row slot
      float mf = floorf(inner[i] * inv_s);
      q_lds[(ix[i]*4 + c)*256 + t] = mf;
    }
  }
  unsigned dmax = 0u;
  if (LEVEL == 2){
    uchar4 mout[8];
    #pragma unroll
    for (int c = 0; c < 4; ++c){
      float res3[8];
      #pragma unroll
      for (int rr = 0; rr < 8; ++rr){
        int mi = (int)q_lds[(rr*4 + c)*256 + t];
        mi = max(-8, min(7, mi));
        float q = s * (float)mi;           // == s2*floorf(...) bit-exactly for small ints
        float vn = ((const float*)&b4[rr])[c] + q;
        ((unsigned char*)&mout[rr])[c] = (unsigned char)(mi + 8);
        res3[rr] = ((const float*)&u4[rr])[c] - vn;   // bit-exact next-level residual
      }
      sort8v(res3);
      float m = 0.0f;
      #pragma unroll
      for (int i = 0; i < 7; ++i) m = fmaxf(m, res3[i+1] - res3[i]);
      dmax = max(dmax, __float_as_uint(m));
    }
    #pragma unroll
    for (int rr = 0; rr < 8; ++rr)
      *(uchar4*)(mcode + (size_t)rr*DT + d0) = mout[rr];
    __syncthreads();
    red[t] = dmax;
    __syncthreads();
    for (int o = 128; o > 0; o >>= 1){
      if (t < o) red[t] = max(red[t], red[t+o]);
      __syncthreads();
    }
    if (t == 0) slots[SL_G3 + b] = red[0];
  } else {
    #pragma unroll
    for (int rr = 0; rr < 8; ++rr){
      ushort4 o;
      #pragma unroll
      for (int c = 0; c < 4; ++c){
        float q = s * q_lds[(rr*4 + c)*256 + t];
        float vn = ((const float*)&b4[rr])[c] + q;
        ((unsigned short*)&o)[c] = f2bf(vn);
      }
      *(ushort4*)(vsumb + (size_t)rr*DT + d0) = o;
    }
  }
}

// transpose: wt[n][l][k] = vsumb[n][k][l] (both bf16); 64(k) x 64(l) tiles
__global__ __launch_bounds__(256) void k_wt(const unsigned short* __restrict__ vsumb,
                                            unsigned short* __restrict__ wt){
  __shared__ unsigned short tile[64][68];
  int t = threadIdx.x;
  int c4 = t & 15, r0 = t >> 4;
  int n = blockIdx.z, k0 = blockIdx.y*64, l0 = blockIdx.x*64;
  const unsigned short* src = vsumb + (size_t)n*DT;
  #pragma unroll
  for (int i = 0; i < 4; ++i){
    int r = r0 + i*16;                     // k index in tile
    ushort4 v = *(const ushort4*)(src + (size_t)(k0+r)*DD2 + l0 + c4*4);
    *(ushort4*)&tile[r][c4*4] = v;
  }
  __syncthreads();
  unsigned short* dst = wt + (size_t)n*DT;
  #pragma unroll
  for (int i = 0; i < 4; ++i){
    int rl = r0 + i*16;                    // l index in tile
    ushort4 o;
    o.x = tile[c4*4+0][rl]; o.y = tile[c4*4+1][rl];
    o.z = tile[c4*4+2][rl]; o.w = tile[c4*4+3][rl];
    *(ushort4*)(dst + (size_t)(l0+rl)*DD1 + k0 + c4*4) = o;
  }
}

// MFMA GEMM: out[b,n,l] = sum_k xb[b,n,k] * wt[n,l,k]; 64(M)x128(N) tile, BK=64, 4 waves
__global__ __launch_bounds__(256) void k_gemm(const unsigned short* __restrict__ xb,
                                              const unsigned short* __restrict__ wt,
                                              float* __restrict__ out){
  __shared__ __align__(16) unsigned short As[64*64];
  __shared__ __align__(16) unsigned short Bs[128*64];
  int t = threadIdx.x;
  int lane = t & 63, wv = t >> 6;
  int n  = blockIdx.z;
  int b0 = blockIdx.y * 64;
  int l0 = blockIdx.x * 128;
  int wm = (wv >> 1) * 32, wn = (wv & 1) * 64;
  int col = lane & 15, quad = lane >> 4;
  int arow = lane >> 3, aseg = lane & 7;
  const unsigned short* wtn = wt + (size_t)n*DT;
  f32x4 acc[2][4] = {};
  for (int k0 = 0; k0 < DD1; k0 += 64){
    #pragma unroll
    for (int i = 0; i < 2; ++i){
      int row = wv*16 + i*8 + arow;
      const unsigned short* g = xb + (((size_t)(b0+row)*NROW + n)*DD1 + k0 + aseg*8);
      async16(g, &As[(wv*16 + i*8)*64]);
    }
    #pragma unroll
    for (int i = 0; i < 4; ++i){
      int row = wv*32 + i*8 + arow;
      const unsigned short* g = wtn + ((size_t)(l0+row)*DD1 + k0 + aseg*8);
      async16(g, &Bs[(wv*32 + i*8)*64]);
    }
    __syncthreads();
    #pragma unroll
    for (int ks = 0; ks < 2; ++ks){
      int kq = ks*32 + quad*8;
      short8 af[2], bfr[4];
      #pragma unroll
      for (int mi = 0; mi < 2; ++mi) af[mi]  = *(const short8*)&As[(wm + mi*16 + col)*64 + kq];
      #pragma unroll
      for (int ni = 0; ni < 4; ++ni) bfr[ni] = *(const short8*)&Bs[(wn + ni*16 + col)*64 + kq];
      #pragma unroll
      for (int mi = 0; mi < 2; ++mi)
        #pragma unroll
        for (int ni = 0; ni < 4; ++ni)
          acc[mi][ni] = __builtin_amdgcn_mfma_f32_16x16x32_bf16(af[mi], bfr[ni], acc[mi][ni], 0, 0, 0);
    }
    __syncthreads();
  }
  #pragma unroll
  for (int mi = 0; mi < 2; ++mi)
    #pragma unroll
    for (int ni = 0; ni < 4; ++ni)
      #pragma unroll
      for (int r = 0; r < 4; ++r){
        int bb = b0 + wm + mi*16 + quad*4 + r;
        int l = l0 + wn + ni*16 + col;
        out[((size_t)bb*NROW + n)*DD2 + l] = acc[mi][ni][r];
      }
}

extern "C" void kernel_launch(void* const* d_in, const int* in_sizes, int n_in,
                              void* d_out, int out_size, void* d_ws, size_t ws_size,
                              hipStream_t stream){
  const float* x  = (const float*)d_in[0];
  const float* U  = (const float*)d_in[1];
  const float* tm = (const float*)d_in[2];
  float* out = (float*)d_out;
  unsigned char*  mcode = (unsigned char*)d_ws;
  unsigned short* vsumb = (unsigned short*)((unsigned char*)d_ws + 16777216);
  unsigned short* xb    = (unsigned short*)((unsigned char*)d_ws + 50331648);
  unsigned char*  code  = (unsigned char*)d_ws + 67108864;
  unsigned short* wt    = (unsigned short*)((unsigned char*)d_ws + 69206016);
  unsigned* meta  = (unsigned*)((unsigned char*)d_ws + 102760448);
  unsigned* slots = (unsigned*)((unsigned char*)d_ws + 102768640);
  (void)in_sizes; (void)n_in; (void)out_size; (void)ws_size;

  k_mmxb    <<<NBLK, 256, 0, stream>>>(U, x, xb, meta, slots);
  // level 2 (deno = 5)
  k_passA2  <<<NBLK, 256, 0, stream>>>(U, slots);
  k_passB<2><<<NBLK, 256, 0, stream>>>(U, mcode, tm, code, meta, slots);
  k_small<2><<<1,   128, 0, stream>>>(U, mcode, tm, meta, slots);
  k_passD<2><<<NBLK, 256, 0, stream>>>(U, mcode, vsumb, code, meta, slots);  // + fused gmax3
  // level 3 (deno = 17)
  k_passB<3><<<NBLK, 256, 0, stream>>>(U, mcode, tm, code, meta, slots);
  k_small<3><<<1,   128, 0, stream>>>(U, mcode, tm, meta, slots);
  k_passD<3><<<NBLK, 256, 0, stream>>>(U, mcode, vsumb, code, meta, slots);
  // epilogue
  k_wt  <<<dim3(DD2/64, DD1/64, NROW), 256, 0, stream>>>(vsumb, wt);
  k_gemm<<<dim3(DD2/128, BATCH/64, NROW), 256, 0, stream>>>(xb, wt, out);
}

// Round 7
// 386.176 us; speedup vs baseline: 1.8007x; 1.0338x over previous
//
#include <hip/hip_runtime.h>
#include <hip/hip_bf16.h>
#include <math.h>

#define NROW 8
#define DT   2097152   // D = D1*D2
#define DD1  2048
#define DD2  1024
#define BATCH 512
#define NBLK 2048      // pass kernels: 2048 blocks x 256 thr x 4 cols == DT

// ws layout (~98.0 MiB):
//  [0)          mcode : NROW*DT uint8  (16,777,216 B)  level-2 m (+8 bias)
//  [16777216)   vsumb : NROW*DT bf16   (33,554,432 B)  final vsum, [n][k][l]
//  [50331648)   xb    : bf16 x         (16,777,216 B)
//  [67108864)   code  : DT bytes       ( 2,097,152 B)
//  [69206016)   wt    : NROW*DT bf16   (33,554,432 B)  [n][l][k]
//  [102760448)  meta  : u32[1412] (hist2 @4, hist3 @132, final_rank @260,
//                        msp f32[896] @388, bits @1284)
//  [102768640)  slots : u32[8192] (SMAX 0, SMIN 2048, G2 4096, G3 6144)
//  [102801408)  fin   : u32[8]   (0: s1 bits, 1: gmax2 bits, 2: gmax3 bits)

#define SL_SMAX 0
#define SL_SMIN 2048
#define SL_G2   4096
#define SL_G3   6144

typedef __attribute__((ext_vector_type(8))) short short8;
typedef __attribute__((ext_vector_type(4))) float f32x4;

__device__ __forceinline__ unsigned fenc(float f){
  unsigned u = __float_as_uint(f);
  return (u & 0x80000000u) ? ~u : (u | 0x80000000u);
}
__device__ __forceinline__ float fdec(unsigned k){
  return (k & 0x80000000u) ? __uint_as_float(k ^ 0x80000000u) : __uint_as_float(~k);
}
__device__ __forceinline__ float sigmoid_ref(float z){
  #pragma clang fp contract(off)
  return 1.0f / (1.0f + expf(-z));
}
__device__ __forceinline__ unsigned short f2bf(float f){
  __hip_bfloat16 h = __float2bfloat16(f);
  return *reinterpret_cast<unsigned short*>(&h);
}
// consistent level-1 base across ALL kernels
__device__ __forceinline__ float base1(float u, float s1, float inv_s1){
  #pragma clang fp contract(off)
  return s1 * floorf(u * inv_s1);
}
// reconstruct level-2 vsum from u + stored m byte (bit-exact vs producer)
__device__ __forceinline__ float vn2_of(float u, unsigned char mb, float s1, float inv_s1, float s2){
  #pragma clang fp contract(off)
  return base1(u, s1, inv_s1) + s2 * (float)((int)mb - 8);
}
__device__ __forceinline__ void async16(const unsigned short* g, unsigned short* l){
  __builtin_amdgcn_global_load_lds((const __attribute__((address_space(1))) unsigned int*)g,
                                   (__attribute__((address_space(3))) unsigned int*)l, 16, 0, 0);
}

// ---- 8-element sorting networks (Batcher odd-even, 19 comparators) ----
#define CSWAPV(a,b) { float _lo=fminf(a,b), _hi=fmaxf(a,b); a=_lo; b=_hi; }
__device__ __forceinline__ void sort8v(float v[8]){
  CSWAPV(v[0],v[1]) CSWAPV(v[2],v[3]) CSWAPV(v[4],v[5]) CSWAPV(v[6],v[7])
  CSWAPV(v[0],v[2]) CSWAPV(v[1],v[3]) CSWAPV(v[4],v[6]) CSWAPV(v[5],v[7])
  CSWAPV(v[1],v[2]) CSWAPV(v[5],v[6])
  CSWAPV(v[0],v[4]) CSWAPV(v[1],v[5]) CSWAPV(v[2],v[6]) CSWAPV(v[3],v[7])
  CSWAPV(v[2],v[4]) CSWAPV(v[3],v[5])
  CSWAPV(v[1],v[2]) CSWAPV(v[3],v[4]) CSWAPV(v[5],v[6])
}
__device__ __forceinline__ void cswapkv(float&av,int&ai,float&bv,int&bi){
  bool sw = (av > bv) || ((av == bv) && (ai > bi));   // lexicographic -> stable
  float nav = sw ? bv : av; float nbv = sw ? av : bv;
  int   nai = sw ? bi : ai; int   nbi = sw ? ai : bi;
  av = nav; bv = nbv; ai = nai; bi = nbi;
}
#define CSWAPK(i,j) cswapkv(v[i],ix[i],v[j],ix[j]);
__device__ __forceinline__ void sort8kv(float v[8], int ix[8]){
  CSWAPK(0,1) CSWAPK(2,3) CSWAPK(4,5) CSWAPK(6,7)
  CSWAPK(0,2) CSWAPK(1,3) CSWAPK(4,6) CSWAPK(5,7)
  CSWAPK(1,2) CSWAPK(5,6)
  CSWAPK(0,4) CSWAPK(1,5) CSWAPK(2,6) CSWAPK(3,7)
  CSWAPK(2,4) CSWAPK(3,5)
  CSWAPK(1,2) CSWAPK(3,4) CSWAPK(5,6)
}

// ---- P1: global min/max of U + x->bf16 convert + zero hists (no atomics) ----
__global__ __launch_bounds__(256) void k_mmxb(const float* __restrict__ U, const float* __restrict__ x,
                                              unsigned short* __restrict__ xb,
                                              unsigned* __restrict__ meta, unsigned* __restrict__ slots){
  __shared__ unsigned redA[256], redB[256];
  int t = threadIdx.x, b = blockIdx.x;
  int gid = b*256 + t;
  if (b == 0 && t < 128){ meta[4+t] = 0u; meta[132+t] = 0u; }
  // x convert: 2,097,152 float4 over 524,288 threads = 4 each
  const float4* x4 = (const float4*)x;
  #pragma unroll
  for (int i = 0; i < 4; ++i){
    int idx = gid + i*524288;
    float4 v = x4[idx];
    ushort4 o;
    o.x = f2bf(v.x); o.y = f2bf(v.y); o.z = f2bf(v.z); o.w = f2bf(v.w);
    *(ushort4*)(xb + (size_t)idx*4) = o;
  }
  // U min/max: 4,194,304 float4 = 8 each
  const float4* U4 = (const float4*)U;
  float mx = -INFINITY, mn = INFINITY;
  #pragma unroll
  for (int i = 0; i < 8; ++i){
    float4 v = U4[gid + i*524288];
    mx = fmaxf(mx, fmaxf(fmaxf(v.x,v.y), fmaxf(v.z,v.w)));
    mn = fminf(mn, fminf(fminf(v.x,v.y), fminf(v.z,v.w)));
  }
  redA[t] = fenc(mx); redB[t] = fenc(mn);
  __syncthreads();
  for (int o = 128; o > 0; o >>= 1){
    if (t < o){ redA[t] = max(redA[t], redA[t+o]); redB[t] = min(redB[t], redB[t+o]); }
    __syncthreads();
  }
  if (t == 0){ slots[SL_SMAX + b] = redA[0]; slots[SL_SMIN + b] = redB[0]; }
}

// ---- tiny finalize kernels: slot arrays -> scalars (order matches R6 exactly) ----
template<int MODE>   // 0: s1 from SMAX/SMIN; 1: gmax2 from G2; 2: gmax3 from G3
__global__ void k_fin(const unsigned* __restrict__ slots, unsigned* __restrict__ fin){
  __shared__ unsigned redA[256], redB[256];
  int t = threadIdx.x;
  if (MODE == 0){
    unsigned vx = 0u, vn = 0xFFFFFFFFu;
    for (int i = t; i < NBLK; i += 256){ vx = max(vx, slots[SL_SMAX+i]); vn = min(vn, slots[SL_SMIN+i]); }
    redA[t] = vx; redB[t] = vn;
    __syncthreads();
    for (int o = 128; o > 0; o >>= 1){
      if (t < o){ redA[t] = max(redA[t], redA[t+o]); redB[t] = min(redB[t], redB[t+o]); }
      __syncthreads();
    }
    if (t == 0){
      float s1 = (fdec(redA[0]) - fdec(redB[0])) / 3.0f;
      fin[0] = __float_as_uint(s1);
    }
  } else {
    const unsigned* s = slots + ((MODE==1) ? SL_G2 : SL_G3);
    unsigned vx = 0u;
    for (int i = t; i < NBLK; i += 256) vx = max(vx, s[i]);
    redA[t] = vx;
    __syncthreads();
    for (int o = 128; o > 0; o >>= 1){
      if (t < o) redA[t] = max(redA[t], redA[t+o]);
      __syncthreads();
    }
    if (t == 0) fin[MODE] = redA[0];
  }
}

// ---- P2: level-2 gmax ----
__global__ __launch_bounds__(256) void k_passA2(const float* __restrict__ U,
                                                const unsigned* __restrict__ fin,
                                                unsigned* __restrict__ slots){
  #pragma clang fp contract(off)
  __shared__ unsigned red[256];
  int t = threadIdx.x, b = blockIdx.x;
  float s1 = __uint_as_float(fin[0]);
  float inv_s1 = 1.0f / s1;
  int d0 = (b*256 + t)*4;
  float4 u[8];
  #pragma unroll
  for (int i = 0; i < 8; ++i) u[i] = *(const float4*)(U + (size_t)i*DT + d0);
  unsigned dmax = 0u;
  #pragma unroll
  for (int c = 0; c < 4; ++c){
    float res[8];
    #pragma unroll
    for (int i = 0; i < 8; ++i){
      float uv = ((const float*)&u[i])[c];
      res[i] = uv - base1(uv, s1, inv_s1);
    }
    sort8v(res);
    float m = 0.0f;
    #pragma unroll
    for (int i = 0; i < 7; ++i) m = fmaxf(m, res[i+1] - res[i]);
    dmax = max(dmax, __float_as_uint(m));   // deltas >= 0: bits order-preserving
  }
  red[t] = dmax;
  __syncthreads();
  for (int o = 128; o > 0; o >>= 1){
    if (t < o) red[t] = max(red[t], red[t+o]);
    __syncthreads();
  }
  if (t == 0) slots[SL_G2 + b] = red[0];
}

// ---- P3/P6: codes + histogram (wave-aggregated: one LDS atomic per distinct code per wave) ----
template<int LEVEL>
__global__ __launch_bounds__(256) void k_passB(const float* __restrict__ U,
                                               const unsigned char* __restrict__ mcode,
                                               const float* __restrict__ tm,
                                               unsigned char* __restrict__ code,
                                               unsigned* __restrict__ meta,
                                               const unsigned* __restrict__ fin){
  #pragma clang fp contract(off)
  __shared__ int hist[128];
  int t = threadIdx.x, b = blockIdx.x;
  int lane = t & 63;
  if (t < 128) hist[t] = 0;
  float s1 = __uint_as_float(fin[0]);
  float inv_s1 = 1.0f / s1;
  float s2 = s1 / 5.0f;
  float gmax = __uint_as_float(fin[(LEVEL==2)?1:2]);
  float inv_gmax = 1.0f / gmax;
  int d0 = (b*256 + t)*4;
  float4 u[8], bb[8];
  #pragma unroll
  for (int i = 0; i < 8; ++i){
    u[i] = *(const float4*)(U + (size_t)i*DT + d0);
    if (LEVEL == 2){
      bb[i].x = base1(u[i].x, s1, inv_s1); bb[i].y = base1(u[i].y, s1, inv_s1);
      bb[i].z = base1(u[i].z, s1, inv_s1); bb[i].w = base1(u[i].w, s1, inv_s1);
    } else {
      uchar4 m4 = *(const uchar4*)(mcode + (size_t)i*DT + d0);
      bb[i].x = vn2_of(u[i].x, m4.x, s1, inv_s1, s2);
      bb[i].y = vn2_of(u[i].y, m4.y, s1, inv_s1, s2);
      bb[i].z = vn2_of(u[i].z, m4.z, s1, inv_s1, s2);
      bb[i].w = vn2_of(u[i].w, m4.w, s1, inv_s1, s2);
    }
  }
  __syncthreads();   // hist zeroed before any atomics
  float thr = sigmoid_ref(tm[d0 >> 11]);
  uchar4 cods;
  unsigned char* cp = (unsigned char*)&cods;
  #pragma unroll
  for (int c = 0; c < 4; ++c){
    float res[8];
    #pragma unroll
    for (int i = 0; i < 8; ++i) res[i] = ((const float*)&u[i])[c] - ((const float*)&bb[i])[c];
    sort8v(res);
    int cd = 0;
    #pragma unroll
    for (int i = 0; i < 7; ++i){
      // bit = rint(sigmoid((dn-thr)/0.01)) == (dn > thr)
      float dn = (res[i+1] - res[i]) * inv_gmax;
      cd = (cd << 1) | ((dn > thr) ? 1 : 0);
    }
    cp[c] = (unsigned char)cd;
    // wave-aggregate: loop over distinct codes present in the wave
    bool pending = true;
    while (true){
      unsigned long long nd = __ballot(pending);
      if (nd == 0ull) break;
      int leader = (int)__ffsll((unsigned long long)nd) - 1;
      int lc = __shfl(cd, leader);
      bool mine = pending && (cd == lc);
      unsigned long long mm = __ballot(mine);
      if (lane == leader) atomicAdd(&hist[lc], (int)__popcll(mm));
      if (mine) pending = false;
    }
  }
  *(uchar4*)(code + d0) = cods;
  __syncthreads();
  if (t < 128){ int h = hist[t]; if (h) atomicAdd((int*)&meta[((LEVEL==2)?4:132) + t], h); }
}

// ---- P4/P7: rank/top-5/msp tables (1 block, 128 threads) ----
template<int LEVEL>
__global__ void k_small(const float* __restrict__ U, const unsigned char* __restrict__ mcode,
                        const float* __restrict__ tm, unsigned* __restrict__ meta,
                        const unsigned* __restrict__ fin){
  #pragma clang fp contract(off)
  __shared__ int cs[128], rk[128], redk[128];
  __shared__ int top_code[5], top_rank[5];
  __shared__ int w0cnt;
  int c = threadIdx.x;                    // 128 threads
  float s1 = __uint_as_float(fin[0]);
  float inv_s1 = 1.0f / s1;
  float s2 = s1 / 5.0f;
  float gmax = __uint_as_float(fin[(LEVEL==2)?1:2]);
  cs[c] = (int)meta[((LEVEL==2)?4:132) + c];
  bool present = cs[c] > 0;
  unsigned long long bm = __ballot(present);
  int lane = c & 63;
  int r = (int)__popcll(bm & ((1ull << lane) - 1ull));
  if (c == 63) w0cnt = (int)__popcll(bm);
  __syncthreads();
  if (c >= 64) r += w0cnt;
  rk[c] = r;
  __syncthreads();
  for (int k = 0; k < 5; ++k){            // top-5 argsort(-counts), ties -> lowest index
    redk[c] = (cs[c] << 7) | (127 - c);
    __syncthreads();
    for (int o = 64; o > 0; o >>= 1){
      if (c < o) redk[c] = max(redk[c], redk[c+o]);
      __syncthreads();
    }
    if (c == 0){
      int best = 127 - (redk[0] & 127);
      top_code[k] = best; top_rank[k] = rk[best];
      cs[best] = -1;
    }
    __syncthreads();
  }
  int besti = -1, sel = 0;
  #pragma unroll
  for (int j = 0; j < 5; ++j){            // argmax first-wins over shared-bit counts
    int inter = __popc(c & top_code[j]);
    if (inter > besti){ besti = inter; sel = j; }
  }
  bool is_top = false;
  #pragma unroll
  for (int j = 0; j < 5; ++j) is_top = is_top || (rk[c] == top_rank[j]);
  ((int*)meta)[260 + c] = is_top ? rk[c] : top_rank[sel];
  // full-fidelity msp/scheme for columns 0..127 (values multiply into w)
  float res[8];
  #pragma unroll
  for (int i = 0; i < 8; ++i){
    size_t off = (size_t)i*DT + c;
    float u = U[off];
    float bval = (LEVEL==2) ? base1(u, s1, inv_s1) : vn2_of(u, mcode[off], s1, inv_s1, s2);
    res[i] = u - bval;
  }
  sort8v(res);
  float thr = sigmoid_ref(tm[c >> 11]);
  unsigned bits = 0;
  float* msp_tab = (float*)(meta + 388);
  #pragma unroll
  for (int i = 0; i < 7; ++i){
    float dn  = (res[i+1] - res[i]) / gmax;
    float z   = (dn - thr) / 0.01f;
    float msp = sigmoid_ref(z);
    msp_tab[c*7 + i] = msp;
    bits |= ((unsigned)(int)rintf(msp)) << i;
  }
  meta[1284 + c] = bits;
}

// ---- P5/P8: quant apply. LEVEL==2: write mcode + fused level-3 gmax slots.
//      LEVEL==3: write final vsum as bf16 [n][k][l]. ----
template<int LEVEL>
__global__ __launch_bounds__(256) void k_passD(const float* __restrict__ U,
                                               unsigned char* __restrict__ mcode,
                                               unsigned short* __restrict__ vsumb,
                                               const unsigned char* __restrict__ code,
                                               unsigned* __restrict__ meta,
                                               const unsigned* __restrict__ fin,
                                               unsigned* __restrict__ slots){
  #pragma clang fp contract(off)
  __shared__ float q_lds[32*256];          // [rr*4+c][t]: scatter slot, bank = t%32 (conflict-free)
  __shared__ unsigned red[256];
  __shared__ int fr_s[128];
  __shared__ unsigned bits_s[128];
  __shared__ float msp_s[896];
  int t = threadIdx.x, b = blockIdx.x;
  float s1 = __uint_as_float(fin[0]);
  float inv_s1 = 1.0f / s1;
  float s2 = s1 / 5.0f;
  float s  = (LEVEL == 2) ? s2 : (s2 / 17.0f);
  float inv_s = 1.0f / s;
  if (t < 128){ fr_s[t] = ((const int*)meta)[260+t]; bits_s[t] = meta[1284+t]; }
  for (int i = t; i < 896; i += 256) msp_s[i] = ((const float*)(meta+388))[i];
  __syncthreads();
  int d0 = (b*256 + t)*4;
  float4 u4[8], b4[8];
  #pragma unroll
  for (int i = 0; i < 8; ++i){
    u4[i] = *(const float4*)(U + (size_t)i*DT + d0);
    if (LEVEL == 2){
      b4[i].x = base1(u4[i].x, s1, inv_s1); b4[i].y = base1(u4[i].y, s1, inv_s1);
      b4[i].z = base1(u4[i].z, s1, inv_s1); b4[i].w = base1(u4[i].w, s1, inv_s1);
    } else {
      uchar4 m4 = *(const uchar4*)(mcode + (size_t)i*DT + d0);
      b4[i].x = vn2_of(u4[i].x, m4.x, s1, inv_s1, s2);
      b4[i].y = vn2_of(u4[i].y, m4.y, s1, inv_s1, s2);
      b4[i].z = vn2_of(u4[i].z, m4.z, s1, inv_s1, s2);
      b4[i].w = vn2_of(u4[i].w, m4.w, s1, inv_s1, s2);
    }
  }
  uchar4 cods = *(const uchar4*)(code + d0);
  const unsigned char* cp = (const unsigned char*)&cods;
  #pragma unroll
  for (int c = 0; c < 4; ++c){
    float v[8]; int ix[8];
    #pragma unroll
    for (int i = 0; i < 8; ++i){
      v[i] = ((const float*)&u4[i])[c] - ((const float*)&b4[i])[c];
      ix[i] = i;
    }
    sort8kv(v, ix);                        // stable: reproduces jnp.argsort
    int cr = fr_s[cp[c]];
    unsigned sb = bits_s[cr];
    float vv[8]; bool bl[8];
    float buf = 0.0f, cnt = 0.0f, g = 1.0f; bool reset = false;
    #pragma unroll
    for (int i = 0; i < 8; ++i){           // reference scan; mean via rcp (<=1.5ulp)
      buf = reset ? v[i] : (buf + v[i]);
      cnt = reset ? 1.0f : (cnt + 1.0f);
      g   = reset ? 1.0f : g;
      float m = buf * __builtin_amdgcn_rcpf(cnt);
      if (i == 7){ vv[7] = g * m; bl[7] = true; }
      else {
        float msp = msp_s[cr*7 + i];
        bool bv = ((sb >> i) & 1u) != 0u;
        vv[i] = bv ? ((g * msp) * m) : 0.0f;
        bl[i] = bv;
        g = bv ? g : (g * (1.0f - msp));
        reset = bv;
      }
    }
    float out = vv[7];
    float inner[8];
    inner[7] = out;
    for (int i = 6; i >= 0; --i){ if (bl[i]) out = vv[i]; inner[i] = out; }
    #pragma unroll
    for (int i = 0; i < 8; ++i){           // scatter floor-count to original-row slot
      float mf = floorf(inner[i] * inv_s);
      q_lds[(ix[i]*4 + c)*256 + t] = mf;
    }
  }
  unsigned dmax = 0u;
  if (LEVEL == 2){
    uchar4 mout[8];
    #pragma unroll
    for (int c = 0; c < 4; ++c){
      float res3[8];
      #pragma unroll
      for (int rr = 0; rr < 8; ++rr){
        int mi = (int)q_lds[(rr*4 + c)*256 + t];
        mi = max(-8, min(7, mi));
        float q = s * (float)mi;           // == s2*floorf(...) bit-exactly for small ints
        float vn = ((const float*)&b4[rr])[c] + q;
        ((unsigned char*)&mout[rr])[c] = (unsigned char)(mi + 8);
        res3[rr] = ((const float*)&u4[rr])[c] - vn;   // bit-exact next-level residual
      }
      sort8v(res3);
      float m = 0.0f;
      #pragma unroll
      for (int i = 0; i < 7; ++i) m = fmaxf(m, res3[i+1] - res3[i]);
      dmax = max(dmax, __float_as_uint(m));
    }
    #pragma unroll
    for (int rr = 0; rr < 8; ++rr)
      *(uchar4*)(mcode + (size_t)rr*DT + d0) = mout[rr];
    __syncthreads();
    red[t] = dmax;
    __syncthreads();
    for (int o = 128; o > 0; o >>= 1){
      if (t < o) red[t] = max(red[t], red[t+o]);
      __syncthreads();
    }
    if (t == 0) slots[SL_G3 + b] = red[0];
  } else {
    #pragma unroll
    for (int rr = 0; rr < 8; ++rr){
      ushort4 o;
      #pragma unroll
      for (int c = 0; c < 4; ++c){
        float q = s * q_lds[(rr*4 + c)*256 + t];
        float vn = ((const float*)&b4[rr])[c] + q;
        ((unsigned short*)&o)[c] = f2bf(vn);
      }
      *(ushort4*)(vsumb + (size_t)rr*DT + d0) = o;
    }
  }
}

// transpose: wt[n][l][k] = vsumb[n][k][l] (both bf16); 64(k) x 64(l) tiles
__global__ __launch_bounds__(256) void k_wt(const unsigned short* __restrict__ vsumb,
                                            unsigned short* __restrict__ wt){
  __shared__ unsigned short tile[64][68];
  int t = threadIdx.x;
  int c4 = t & 15, r0 = t >> 4;
  int n = blockIdx.z, k0 = blockIdx.y*64, l0 = blockIdx.x*64;
  const unsigned short* src = vsumb + (size_t)n*DT;
  #pragma unroll
  for (int i = 0; i < 4; ++i){
    int r = r0 + i*16;                     // k index in tile
    ushort4 v = *(const ushort4*)(src + (size_t)(k0+r)*DD2 + l0 + c4*4);
    *(ushort4*)&tile[r][c4*4] = v;
  }
  __syncthreads();
  unsigned short* dst = wt + (size_t)n*DT;
  #pragma unroll
  for (int i = 0; i < 4; ++i){
    int rl = r0 + i*16;                    // l index in tile
    ushort4 o;
    o.x = tile[c4*4+0][rl]; o.y = tile[c4*4+1][rl];
    o.z = tile[c4*4+2][rl]; o.w = tile[c4*4+3][rl];
    *(ushort4*)(dst + (size_t)(l0+rl)*DD1 + k0 + c4*4) = o;
  }
}

// MFMA GEMM: out[b,n,l] = sum_k xb[b,n,k] * wt[n,l,k]; 64(M)x128(N) tile, BK=64, 4 waves
__global__ __launch_bounds__(256) void k_gemm(const unsigned short* __restrict__ xb,
                                              const unsigned short* __restrict__ wt,
                                              float* __restrict__ out){
  __shared__ __align__(16) unsigned short As[64*64];
  __shared__ __align__(16) unsigned short Bs[128*64];
  int t = threadIdx.x;
  int lane = t & 63, wv = t >> 6;
  int n  = blockIdx.z;
  int b0 = blockIdx.y * 64;
  int l0 = blockIdx.x * 128;
  int wm = (wv >> 1) * 32, wn = (wv & 1) * 64;
  int col = lane & 15, quad = lane >> 4;
  int arow = lane >> 3, aseg = lane & 7;
  const unsigned short* wtn = wt + (size_t)n*DT;
  f32x4 acc[2][4] = {};
  for (int k0 = 0; k0 < DD1; k0 += 64){
    #pragma unroll
    for (int i = 0; i < 2; ++i){
      int row = wv*16 + i*8 + arow;
      const unsigned short* g = xb + (((size_t)(b0+row)*NROW + n)*DD1 + k0 + aseg*8);
      async16(g, &As[(wv*16 + i*8)*64]);
    }
    #pragma unroll
    for (int i = 0; i < 4; ++i){
      int row = wv*32 + i*8 + arow;
      const unsigned short* g = wtn + ((size_t)(l0+row)*DD1 + k0 + aseg*8);
      async16(g, &Bs[(wv*32 + i*8)*64]);
    }
    __syncthreads();
    #pragma unroll
    for (int ks = 0; ks < 2; ++ks){
      int kq = ks*32 + quad*8;
      short8 af[2], bfr[4];
      #pragma unroll
      for (int mi = 0; mi < 2; ++mi) af[mi]  = *(const short8*)&As[(wm + mi*16 + col)*64 + kq];
      #pragma unroll
      for (int ni = 0; ni < 4; ++ni) bfr[ni] = *(const short8*)&Bs[(wn + ni*16 + col)*64 + kq];
      #pragma unroll
      for (int mi = 0; mi < 2; ++mi)
        #pragma unroll
        for (int ni = 0; ni < 4; ++ni)
          acc[mi][ni] = __builtin_amdgcn_mfma_f32_16x16x32_bf16(af[mi], bfr[ni], acc[mi][ni], 0, 0, 0);
    }
    __syncthreads();
  }
  #pragma unroll
  for (int mi = 0; mi < 2; ++mi)
    #pragma unroll
    for (int ni = 0; ni < 4; ++ni)
      #pragma unroll
      for (int r = 0; r < 4; ++r){
        int bb = b0 + wm + mi*16 + quad*4 + r;
        int l = l0 + wn + ni*16 + col;
        out[((size_t)bb*NROW + n)*DD2 + l] = acc[mi][ni][r];
      }
}

extern "C" void kernel_launch(void* const* d_in, const int* in_sizes, int n_in,
                              void* d_out, int out_size, void* d_ws, size_t ws_size,
                              hipStream_t stream){
  const float* x  = (const float*)d_in[0];
  const float* U  = (const float*)d_in[1];
  const float* tm = (const float*)d_in[2];
  float* out = (float*)d_out;
  unsigned char*  mcode = (unsigned char*)d_ws;
  unsigned short* vsumb = (unsigned short*)((unsigned char*)d_ws + 16777216);
  unsigned short* xb    = (unsigned short*)((unsigned char*)d_ws + 50331648);
  unsigned char*  code  = (unsigned char*)d_ws + 67108864;
  unsigned short* wt    = (unsigned short*)((unsigned char*)d_ws + 69206016);
  unsigned* meta  = (unsigned*)((unsigned char*)d_ws + 102760448);
  unsigned* slots = (unsigned*)((unsigned char*)d_ws + 102768640);
  unsigned* fin   = (unsigned*)((unsigned char*)d_ws + 102801408);
  (void)in_sizes; (void)n_in; (void)out_size; (void)ws_size;

  k_mmxb    <<<NBLK, 256, 0, stream>>>(U, x, xb, meta, slots);
  k_fin<0>  <<<1,    256, 0, stream>>>(slots, fin);
  // level 2 (deno = 5)
  k_passA2  <<<NBLK, 256, 0, stream>>>(U, fin, slots);
  k_fin<1>  <<<1,    256, 0, stream>>>(slots, fin);
  k_passB<2><<<NBLK, 256, 0, stream>>>(U, mcode, tm, code, meta, fin);
  k_small<2><<<1,   128, 0, stream>>>(U, mcode, tm, meta, fin);
  k_passD<2><<<NBLK, 256, 0, stream>>>(U, mcode, vsumb, code, meta, fin, slots);  // + fused gmax3 slots
  k_fin<2>  <<<1,    256, 0, stream>>>(slots, fin);
  // level 3 (deno = 17)
  k_passB<3><<<NBLK, 256, 0, stream>>>(U, mcode, tm, code, meta, fin);
  k_small<3><<<1,   128, 0, stream>>>(U, mcode, tm, meta, fin);
  k_passD<3><<<NBLK, 256, 0, stream>>>(U, mcode, vsumb, code, meta, fin, slots);
  // epilogue
  k_wt  <<<dim3(DD2/64, DD1/64, NROW), 256, 0, stream>>>(vsumb, wt);
  k_gemm<<<dim3(DD2/128, BATCH/64, NROW), 256, 0, stream>>>(xb, wt, out);
}